// Round 1
// baseline (314.425 us; speedup 1.0000x reference)
//
#include <hip/hip_runtime.h>

// Depthwise 7x7 true-convolution (flipped kernel, SAME zero pad) + mish.
// x: [16,64,256,256] f32, kernel: [7,7] f32 (shared by all planes).
// y[i,j] = sum_{p,q} kernel[p][q] * x[i+3-p, j+3-q];  out = y*tanh(softplus(y))
//        = y * (1 - 2/((1+e^y)^2 + 1))

#define HW 256
#define TILE_W 64
#define TILE_H 16
// LDS tile: rows 16+6=22, cols 64+8=72 (4-col halo both sides => float4-aligned
// global loads; left halo of 4 covers the needed 3, col 0 <-> global col0-4)
#define LROWS 22
#define LCOLS 72

__device__ __forceinline__ float mish_f(float y) {
    float t = __expf(y);            // inf-safe: d -> inf -> 2/d -> 0 -> y*1
    float u = 1.0f + t;
    float d = __fmaf_rn(u, u, 1.0f);
    return y * (1.0f - __fdividef(2.0f, d));
}

__global__ __launch_bounds__(256, 4)
void dwconv7_mish_kernel(const float* __restrict__ x,
                         const float* __restrict__ kern,
                         float* __restrict__ out) {
    __shared__ float smem[LROWS * LCOLS];

    const int tx = threadIdx.x & 15;        // 16 threads wide * 4 cols each
    const int ty = threadIdx.x >> 4;        // 16 rows
    const int col0 = blockIdx.x * TILE_W;
    const int row0 = blockIdx.y * TILE_H;
    const int plane = blockIdx.z;           // b*64 + c

    const float* __restrict__ xp = x + (size_t)plane * (HW * HW);
    float* __restrict__ op = out + (size_t)plane * (HW * HW);

    // Flipped kernel into SGPRs: kf[r][q] = kern[6-r][6-q]
    float kf[7][7];
    #pragma unroll
    for (int r = 0; r < 7; ++r) {
        #pragma unroll
        for (int q = 0; q < 7; ++q) {
            int bits = __builtin_amdgcn_readfirstlane(
                __float_as_int(kern[(6 - r) * 7 + (6 - q)]));
            kf[r][q] = __int_as_float(bits);
        }
    }

    // Stage input tile (22 x 72 floats) as float4 slots: 22*18 = 396 slots.
    #pragma unroll
    for (int it = 0; it < 2; ++it) {
        int s = threadIdx.x + it * 256;
        if (s < LROWS * (LCOLS / 4)) {
            int r  = s / (LCOLS / 4);       // 0..21
            int c4 = s - r * (LCOLS / 4);   // 0..17
            int gr = row0 - 3 + r;
            int gc = col0 - 4 + c4 * 4;     // always 16B aligned
            float4 v = make_float4(0.f, 0.f, 0.f, 0.f);
            if ((unsigned)gr < (unsigned)HW && (unsigned)gc < (unsigned)HW) {
                v = *(const float4*)(xp + gr * HW + gc);  // fully in or out
            }
            *(float4*)(&smem[r * LCOLS + c4 * 4]) = v;
        }
    }
    __syncthreads();

    // Each thread: 4 consecutive output cols at (row0+ty, col0+4*tx..+3).
    // Needs LDS cols 4tx+1 .. 4tx+10 -> three aligned float4 at 4tx,+4,+8.
    float acc0 = 0.f, acc1 = 0.f, acc2 = 0.f, acc3 = 0.f;
    #pragma unroll
    for (int r = 0; r < 7; ++r) {
        const float* rowp = &smem[(ty + r) * LCOLS + tx * 4];
        float4 va = *(const float4*)(rowp);
        float4 vb = *(const float4*)(rowp + 4);
        float4 vc = *(const float4*)(rowp + 8);
        float v[12] = {va.x, va.y, va.z, va.w,
                       vb.x, vb.y, vb.z, vb.w,
                       vc.x, vc.y, vc.z, vc.w};
        #pragma unroll
        for (int q = 0; q < 7; ++q) {
            float w = kf[r][q];
            acc0 = fmaf(v[1 + q], w, acc0);
            acc1 = fmaf(v[2 + q], w, acc1);
            acc2 = fmaf(v[3 + q], w, acc2);
            acc3 = fmaf(v[4 + q], w, acc3);
        }
    }

    float4 o;
    o.x = mish_f(acc0);
    o.y = mish_f(acc1);
    o.z = mish_f(acc2);
    o.w = mish_f(acc3);
    *(float4*)(op + (row0 + ty) * HW + col0 + tx * 4) = o;
}

extern "C" void kernel_launch(void* const* d_in, const int* in_sizes, int n_in,
                              void* d_out, int out_size, void* d_ws, size_t ws_size,
                              hipStream_t stream) {
    const float* x = (const float*)d_in[0];
    const float* k = (const float*)d_in[1];
    float* out = (float*)d_out;

    dim3 grid(HW / TILE_W, HW / TILE_H, 16 * 64);  // 4 x 16 x 1024
    dim3 block(256);
    dwconv7_mish_kernel<<<grid, block, 0, stream>>>(x, k, out);
}

// Round 2
// 181.198 us; speedup vs baseline: 1.7353x; 1.7353x over previous
//
#include <hip/hip_runtime.h>

// Depthwise 7x7 true-convolution (flipped kernel, SAME zero pad) + mish.
// x: [16,64,256,256] f32, kernel: [7,7] f32 (shared by all planes).
// y[i,j] = sum_{p,q} kernel[p][q] * x[i+3-p, j+3-q];  out = y*(1 - 2/((1+e^y)^2+1))
//
// Tile: 64 wide x 32 high per block (256 threads: tx=tid&7 -> 8 cols each,
// ty=tid>>3 -> 1 row each). LDS input tile 38 rows x 72 cols stored at row
// stride 73 (odd) => every ds_read_b32 tap is exactly 2-way banked (free):
// bank = (9*ty + 8*tx + c) mod 32; 9*ty spans all residues mod 8.

#define HW 256
#define TILE_W 64
#define TILE_H 32
#define LR 38          // 32 + 6 halo rows
#define RS 73          // row stride in floats (odd!), data cols 0..71 used
#define NSLOT (38*18)  // float4 staging slots (72 cols = 18 float4 per row)

__device__ __forceinline__ float mish_f(float y) {
    float t = __expf(y);            // inf-safe: u^2 -> inf -> 2/d -> 0 -> y*1
    float u = 1.0f + t;
    float d = __fmaf_rn(u, u, 1.0f);
    return y * (1.0f - __fdividef(2.0f, d));
}

__global__ __launch_bounds__(256, 4)
void dwconv7_mish_kernel(const float* __restrict__ x,
                         const float* __restrict__ kern,
                         float* __restrict__ out) {
    __shared__ float smem[LR * RS];

    const int tid = threadIdx.x;
    const int tx = tid & 7;          // 8 threads wide, 8 cols each
    const int ty = tid >> 3;         // 32 rows
    const int col0 = blockIdx.x * TILE_W;
    const int row0 = blockIdx.y * TILE_H;
    const int plane = blockIdx.z;    // b*64 + c

    const float* __restrict__ xp = x + (size_t)plane * (HW * HW);
    float* __restrict__ op = out + (size_t)plane * (HW * HW);

    // Flipped kernel into SGPRs: kf[r*7+q] = kern[6-r][6-q]
    float kf[49];
    #pragma unroll
    for (int i = 0; i < 49; ++i) {
        int r = i / 7, q = i - r * 7;
        int bits = __builtin_amdgcn_readfirstlane(
            __float_as_int(kern[(6 - r) * 7 + (6 - q)]));
        kf[i] = __int_as_float(bits);
    }

    // Stage input tile: 38 rows x 72 cols, float4-aligned global loads
    // (gc = col0-4 + 4*c4 always 16B aligned; a float4 is fully in or out).
    // LDS writes are 4x b32 at odd row stride.
    #pragma unroll
    for (int it = 0; it < 3; ++it) {
        int s = tid + it * 256;
        if (s < NSLOT) {
            int r  = s / 18;
            int c4 = s - r * 18;
            int gr = row0 - 3 + r;
            int gc = col0 - 4 + c4 * 4;
            float4 v = make_float4(0.f, 0.f, 0.f, 0.f);
            if ((unsigned)gr < (unsigned)HW && (unsigned)gc < (unsigned)HW) {
                v = *(const float4*)(xp + gr * HW + gc);
            }
            float* d = &smem[r * RS + c4 * 4];
            d[0] = v.x; d[1] = v.y; d[2] = v.z; d[3] = v.w;
        }
    }
    __syncthreads();

    // Each thread: 8 consecutive output cols at row row0+ty, cols col0+8tx..+7.
    // Taps for output col (8tx+j): LDS cols 8tx+1+j+q, q=0..6 -> window of 14.
    float acc[8];
    #pragma unroll
    for (int j = 0; j < 8; ++j) acc[j] = 0.f;

    #pragma unroll
    for (int r = 0; r < 7; ++r) {
        const float* rp = &smem[(ty + r) * RS + tx * 8 + 1];
        float v[14];
        #pragma unroll
        for (int k = 0; k < 14; ++k) v[k] = rp[k];
        #pragma unroll
        for (int q = 0; q < 7; ++q) {
            float w = kf[r * 7 + q];
            #pragma unroll
            for (int j = 0; j < 8; ++j) {
                acc[j] = fmaf(v[j + q], w, acc[j]);
            }
        }
    }

    float4 o0, o1;
    o0.x = mish_f(acc[0]); o0.y = mish_f(acc[1]);
    o0.z = mish_f(acc[2]); o0.w = mish_f(acc[3]);
    o1.x = mish_f(acc[4]); o1.y = mish_f(acc[5]);
    o1.z = mish_f(acc[6]); o1.w = mish_f(acc[7]);

    float* dst = op + (row0 + ty) * HW + col0 + tx * 8;
    *(float4*)(dst)     = o0;
    *(float4*)(dst + 4) = o1;
}

extern "C" void kernel_launch(void* const* d_in, const int* in_sizes, int n_in,
                              void* d_out, int out_size, void* d_ws, size_t ws_size,
                              hipStream_t stream) {
    const float* x = (const float*)d_in[0];
    const float* k = (const float*)d_in[1];
    float* out = (float*)d_out;

    dim3 grid(HW / TILE_W, HW / TILE_H, 16 * 64);  // 4 x 8 x 1024
    dim3 block(256);
    dwconv7_mish_kernel<<<grid, block, 0, stream>>>(x, k, out);
}

// Round 3
// 171.558 us; speedup vs baseline: 1.8328x; 1.0562x over previous
//
#include <hip/hip_runtime.h>

// Depthwise 7x7 true-convolution (flipped kernel, SAME zero pad) + mish.
// x: [16,64,256,256] f32, kernel: [7,7] f32 (shared by all planes).
//
// Tile 128w x 64h per block, 256 threads, each thread 8w x 4h outputs.
// Input tile 136w x 70h staged in LDS as float4 granules, row stride 40
// granules (160 floats, 640B == 0 mod 32 banks). XOR swizzle on the granule
// index: phys = g ^ ((row>>2)&7). Per ds_read_b128 instruction the 64 lanes
// then cover all 8 granule residues x 8 lanes = 8 words/bank (the b128
// hardware minimum) -> provably conflict-free, while a thread's 4 output
// rows share their 10-row input window (vertical register reuse).

#define HW 256
#define TILE_W 128
#define TILE_H 64
#define LR 70            // input tile rows (64 + 6 halo)
#define NGD 34           // data granules per row (136 cols: 4-left halo, aligned)
#define NGP 40           // padded granule row stride (160 floats, 640 B)
#define NSLOT (LR * NGD) // 2380 staging granules

__device__ __forceinline__ float mish_f(float y) {
    float t = __expf(y);            // inf-safe: d -> inf -> 2/d -> 0 -> y*1
    float u = 1.0f + t;
    float d = __fmaf_rn(u, u, 1.0f);
    return y * (1.0f - __fdividef(2.0f, d));
}

__global__ __launch_bounds__(256, 3)
void dwconv7_mish_kernel(const float* __restrict__ x,
                         const float* __restrict__ kern,
                         float* __restrict__ out) {
    __shared__ float4 smem4[LR * NGP];   // 44,800 B -> 3 blocks/CU

    const int tid = threadIdx.x;
    const int tx = tid & 15;             // 16 strips x 8 cols = 128 wide
    const int ty = tid >> 4;             // 16 x 4 rows = 64 tall
    const int col0 = blockIdx.x * TILE_W;
    const int row0 = blockIdx.y * TILE_H;
    const int plane = blockIdx.z;        // b*64 + c

    const float* __restrict__ xp = x + (size_t)plane * (HW * HW);
    float* __restrict__ op = out + (size_t)plane * (HW * HW);

    // Flipped kernel into SGPRs: kf[p*7+q] = kern[6-p][6-q]
    float kf[49];
    #pragma unroll
    for (int i = 0; i < 49; ++i) {
        int p = i / 7, q = i - p * 7;
        int bits = __builtin_amdgcn_readfirstlane(
            __float_as_int(kern[(6 - p) * 7 + (6 - q)]));
        kf[i] = __int_as_float(bits);
    }

    // Stage input tile. Global float4 loads are 16B-aligned (gc = col0-4+4*c4),
    // so each granule is fully in-bounds or fully zero. LDS write goes to the
    // XOR-swizzled slot.
    #pragma unroll
    for (int it = 0; it < 10; ++it) {
        int s = tid + it * 256;
        if (s < NSLOT) {
            int r  = s / NGD;
            int c4 = s - r * NGD;
            int gr = row0 - 3 + r;
            int gc = col0 - 4 + c4 * 4;
            float4 v = make_float4(0.f, 0.f, 0.f, 0.f);
            if ((unsigned)gr < (unsigned)HW && (unsigned)gc < (unsigned)HW) {
                v = *(const float4*)(xp + gr * HW + gc);
            }
            int sb = (r >> 2) & 7;
            smem4[r * NGP + (c4 ^ sb)] = v;
        }
    }
    __syncthreads();

    // Each thread: output tile rows 4*ty+j (j=0..3), cols 8*tx..8*tx+7.
    // Input window: LDS rows 4*ty .. 4*ty+9, granules 2*tx .. 2*tx+3
    // (LDS cols 8*tx .. 8*tx+15 = data cols 8*tx-4 .. 8*tx+11).
    float acc[4][8];
    #pragma unroll
    for (int j = 0; j < 4; ++j)
        #pragma unroll
        for (int c = 0; c < 8; ++c) acc[j][c] = 0.f;

    const int g0 = 2 * tx;
    #pragma unroll
    for (int rr = 0; rr < 10; ++rr) {
        const int lr = 4 * ty + rr;
        const int sb = (lr >> 2) & 7;
        const float4* base = &smem4[lr * NGP];
        float4 va = base[(g0 + 0) ^ sb];
        float4 vb = base[(g0 + 1) ^ sb];
        float4 vc = base[(g0 + 2) ^ sb];
        float4 vd = base[(g0 + 3) ^ sb];
        float v[16] = {va.x, va.y, va.z, va.w,
                       vb.x, vb.y, vb.z, vb.w,
                       vc.x, vc.y, vc.z, vc.w,
                       vd.x, vd.y, vd.z, vd.w};
        // input row lr feeds output row j with kernel row p = rr - j
        #pragma unroll
        for (int j = 0; j < 4; ++j) {
            if (rr - j >= 0 && rr - j <= 6) {   // compile-time after unroll
                const int p = rr - j;
                #pragma unroll
                for (int q = 0; q < 7; ++q) {
                    float w = kf[p * 7 + q];
                    #pragma unroll
                    for (int c = 0; c < 8; ++c) {
                        acc[j][c] = fmaf(v[c + q + 1], w, acc[j][c]);
                    }
                }
            }
        }
    }

    #pragma unroll
    for (int j = 0; j < 4; ++j) {
        float4 o0, o1;
        o0.x = mish_f(acc[j][0]); o0.y = mish_f(acc[j][1]);
        o0.z = mish_f(acc[j][2]); o0.w = mish_f(acc[j][3]);
        o1.x = mish_f(acc[j][4]); o1.y = mish_f(acc[j][5]);
        o1.z = mish_f(acc[j][6]); o1.w = mish_f(acc[j][7]);
        float* dst = op + (row0 + 4 * ty + j) * HW + col0 + tx * 8;
        *(float4*)(dst)     = o0;
        *(float4*)(dst + 4) = o1;
    }
}

extern "C" void kernel_launch(void* const* d_in, const int* in_sizes, int n_in,
                              void* d_out, int out_size, void* d_ws, size_t ws_size,
                              hipStream_t stream) {
    const float* x = (const float*)d_in[0];
    const float* k = (const float*)d_in[1];
    float* out = (float*)d_out;

    dim3 grid(HW / TILE_W, HW / TILE_H, 16 * 64);  // 2 x 4 x 1024
    dim3 block(256);
    dwconv7_mish_kernel<<<grid, block, 0, stream>>>(x, k, out);
}